// Round 5
// baseline (679.823 us; speedup 1.0000x reference)
//
#include <hip/hip_runtime.h>
#include <hip/hip_fp16.h>
#include <math.h>

// GCN forward: GCNConv(6->4, self-loops, sym-norm) -> tanh -> mean-pool -> fc1+relu -> fc3
// agg[c] = dinv[c] * ( sum_{edges r->c} p[r] + p[c] ) + conv_b, p[i] = (W x[i]) * dinv[i]
//
// R5: k_acc was invariant ~350 us across traffic/block-size changes -> suspect CAS-loop
// lowering of shared-float atomicAdd. (a) unsafeAtomicAdd -> native ds_add_f32;
// (b) SUB=2 blocks per partition (978 blocks, ~30 waves/CU) + global partial tiles
// + separate k_tanh epilogue; (c) 8 gathers in flight per thread iteration.

constexpr int NP = 1024;        // nodes per partition
constexpr int SHIFT = 10;
constexpr unsigned MASK = 1023;
constexpr int NPART_MAX = 512;  // scan width; P = ceil(500k/1024) = 489
constexpr int EPB = 8192;       // edges per k_bin block
constexpr int BINB = 512;       // k_bin block size
constexpr int BT = 512;         // per-partition kernel block size

struct alignas(8) Half4 { __half2 a, b; };

// ---------------- binning path ----------------

__global__ __launch_bounds__(BINB) void k_bin(const int* __restrict__ row,
                                              const int* __restrict__ col, int E,
                                              int P, int cap, int* __restrict__ cursor,
                                              unsigned* __restrict__ binned) {
    __shared__ unsigned lbuf[EPB];          // 32 KB, sorted-by-partition edge buffer
    __shared__ int lcount[NPART_MAX];
    __shared__ int lbase[NPART_MAX];
    __shared__ int gbase[NPART_MAX];
    __shared__ int lpos[NPART_MAX];
    __shared__ int sc[NPART_MAX];

    int t = threadIdx.x;
    int start = blockIdx.x * EPB;
    int end = min(start + EPB, E);
    bool full = (end - start) == EPB;

    lcount[t] = 0; lpos[t] = 0;
    __syncthreads();

    // phase 1: count per partition (vectorized)
    if (full) {
        const int4* c4 = (const int4*)(col + start);
#pragma unroll
        for (int i = 0; i < EPB / 4 / BINB; ++i) {
            int4 c = c4[t + i * BINB];
            atomicAdd(&lcount[c.x >> SHIFT], 1);
            atomicAdd(&lcount[c.y >> SHIFT], 1);
            atomicAdd(&lcount[c.z >> SHIFT], 1);
            atomicAdd(&lcount[c.w >> SHIFT], 1);
        }
    } else {
        for (int e = start + t; e < end; e += BINB)
            atomicAdd(&lcount[col[e] >> SHIFT], 1);
    }
    __syncthreads();

    // phase 2: exclusive scan (Hillis-Steele, 512 wide)
    sc[t] = lcount[t];
    __syncthreads();
    for (int off = 1; off < NPART_MAX; off <<= 1) {
        int v = (t >= off) ? sc[t - off] : 0;
        __syncthreads();
        sc[t] += v;
        __syncthreads();
    }
    lbase[t] = sc[t] - lcount[t];
    if (t < P) {
        int c = lcount[t];
        gbase[t] = (c > 0) ? atomicAdd(&cursor[t], c) : 0;
    }
    __syncthreads();

    // phase 3: place edges into LDS sorted by partition
    if (full) {
        const int4* c4 = (const int4*)(col + start);
        const int4* r4 = (const int4*)(row + start);
#pragma unroll
        for (int i = 0; i < EPB / 4 / BINB; ++i) {
            int4 c = c4[t + i * BINB];
            int4 r = r4[t + i * BINB];
            int part, slot;
            part = c.x >> SHIFT; slot = atomicAdd(&lpos[part], 1);
            lbuf[lbase[part] + slot] = ((unsigned)r.x << SHIFT) | ((unsigned)c.x & MASK);
            part = c.y >> SHIFT; slot = atomicAdd(&lpos[part], 1);
            lbuf[lbase[part] + slot] = ((unsigned)r.y << SHIFT) | ((unsigned)c.y & MASK);
            part = c.z >> SHIFT; slot = atomicAdd(&lpos[part], 1);
            lbuf[lbase[part] + slot] = ((unsigned)r.z << SHIFT) | ((unsigned)c.z & MASK);
            part = c.w >> SHIFT; slot = atomicAdd(&lpos[part], 1);
            lbuf[lbase[part] + slot] = ((unsigned)r.w << SHIFT) | ((unsigned)c.w & MASK);
        }
    } else {
        for (int e = start + t; e < end; e += BINB) {
            int r = row[e], c = col[e];
            int part = c >> SHIFT;
            int slot = atomicAdd(&lpos[part], 1);
            lbuf[lbase[part] + slot] = ((unsigned)r << SHIFT) | ((unsigned)c & MASK);
        }
    }
    __syncthreads();

    // phase 4: coalesced flush, one wave per partition round-robin
    int lane = t & 63;
    int wave = t >> 6;
    const int nwaves = BINB / 64;
    for (int part = wave; part < P; part += nwaves) {
        int cnt = lcount[part];
        if (cnt == 0) continue;
        int lb = lbase[part];
        int gb = gbase[part];
        unsigned* dst = binned + (size_t)part * cap;
        for (int j = lane; j < cnt; j += 64) {
            int slot = gb + j;
            if (slot < cap) dst[slot] = lbuf[lb + j];
        }
    }
}

// per-partition: deg from bin (LDS), then p = (W x)*dinv -> fp16x4, store dinv
__global__ __launch_bounds__(BT) void k_part_node(const unsigned* __restrict__ binned,
                                                  const int* __restrict__ cursor, int cap,
                                                  const float* __restrict__ x,
                                                  const float* __restrict__ conv_w, int n,
                                                  Half4* __restrict__ ph,
                                                  float* __restrict__ dinvg) {
    __shared__ int degs[NP];
    __shared__ float w[24];
    int part = blockIdx.x;
    int tid = threadIdx.x;
    if (tid < 24) w[tid] = conv_w[tid];
    for (int i = tid; i < NP; i += BT) degs[i] = 0;
    __syncthreads();
    int cnt = min(cursor[part], cap);
    const unsigned* bin = binned + (size_t)part * cap;
    const uint4* bin4 = (const uint4*)bin;
    int cnt4 = cnt >> 2;
    for (int i = tid; i < cnt4; i += BT) {
        uint4 v = bin4[i];
        atomicAdd(&degs[v.x & MASK], 1);
        atomicAdd(&degs[v.y & MASK], 1);
        atomicAdd(&degs[v.z & MASK], 1);
        atomicAdd(&degs[v.w & MASK], 1);
    }
    for (int e = (cnt4 << 2) + tid; e < cnt; e += BT)
        atomicAdd(&degs[bin[e] & MASK], 1);
    __syncthreads();
    int base = part * NP;
    for (int i = tid; i < NP; i += BT) {
        int node = base + i;
        if (node >= n) continue;
        float dinv = rsqrtf((float)(degs[i] + 1));   // +1 self-loop
        const float* xr = x + (size_t)node * 6;
        float2 a = *(const float2*)xr;
        float2 b = *(const float2*)(xr + 2);
        float2 cc = *(const float2*)(xr + 4);
        float xv[6] = {a.x, a.y, b.x, b.y, cc.x, cc.y};
        float h0 = 0.f, h1 = 0.f, h2 = 0.f, h3 = 0.f;
#pragma unroll
        for (int j = 0; j < 6; ++j) {
            h0 += xv[j] * w[j];
            h1 += xv[j] * w[6 + j];
            h2 += xv[j] * w[12 + j];
            h3 += xv[j] * w[18 + j];
        }
        Half4 o;
        o.a = __floats2half2_rn(h0 * dinv, h1 * dinv);
        o.b = __floats2half2_rn(h2 * dinv, h3 * dinv);
        ph[node] = o;
        dinvg[node] = dinv;
    }
}

__device__ __forceinline__ void acc_edge(float* __restrict__ S, unsigned v,
                                         const Half4& h) {
    float2 a = __half22float2(h.a), b = __half22float2(h.b);
    float* s = &S[(v & MASK) * 5];
    unsafeAtomicAdd(s + 0, a.x);
    unsafeAtomicAdd(s + 1, a.y);
    unsafeAtomicAdd(s + 2, b.x);
    unsafeAtomicAdd(s + 3, b.y);
}

// SUB blocks per partition: each accumulates its slice into a private LDS tile
// with native ds_add_f32, then flushes with plain coalesced stores to Spart.
__global__ __launch_bounds__(BT) void k_acc2(const unsigned* __restrict__ binned,
                                             const int* __restrict__ cursor, int cap,
                                             const Half4* __restrict__ ph, int SUB,
                                             float4* __restrict__ Spart) {
    __shared__ float S[NP * 5];          // stride 5 (coprime with 32 banks)
    int part = blockIdx.x / SUB;
    int sub = blockIdx.x - part * SUB;
    int tid = threadIdx.x;
    for (int i = tid; i < NP * 5; i += BT) S[i] = 0.f;
    __syncthreads();
    int cnt = min(cursor[part], cap);
    const unsigned* bin = binned + (size_t)part * cap;
    const uint4* bin4 = (const uint4*)bin;
    int cnt4 = cnt >> 2;
    int chunk4 = (cnt4 + SUB - 1) / SUB;
    int s4 = sub * chunk4;
    int e4 = min(cnt4, s4 + chunk4);

    int i = s4 + tid;
    // 2-way unrolled: 8 gathers in flight
    for (; i + BT < e4; i += 2 * BT) {
        uint4 v0 = bin4[i];
        uint4 v1 = bin4[i + BT];
        Half4 h0 = ph[v0.x >> SHIFT];
        Half4 h1 = ph[v0.y >> SHIFT];
        Half4 h2 = ph[v0.z >> SHIFT];
        Half4 h3 = ph[v0.w >> SHIFT];
        Half4 h4 = ph[v1.x >> SHIFT];
        Half4 h5 = ph[v1.y >> SHIFT];
        Half4 h6 = ph[v1.z >> SHIFT];
        Half4 h7 = ph[v1.w >> SHIFT];
        acc_edge(S, v0.x, h0); acc_edge(S, v0.y, h1);
        acc_edge(S, v0.z, h2); acc_edge(S, v0.w, h3);
        acc_edge(S, v1.x, h4); acc_edge(S, v1.y, h5);
        acc_edge(S, v1.z, h6); acc_edge(S, v1.w, h7);
    }
    for (; i < e4; i += BT) {
        uint4 v = bin4[i];
        Half4 h0 = ph[v.x >> SHIFT];
        Half4 h1 = ph[v.y >> SHIFT];
        Half4 h2 = ph[v.z >> SHIFT];
        Half4 h3 = ph[v.w >> SHIFT];
        acc_edge(S, v.x, h0); acc_edge(S, v.y, h1);
        acc_edge(S, v.z, h2); acc_edge(S, v.w, h3);
    }
    if (sub == SUB - 1) {   // scalar tail edges
        for (int e = (cnt4 << 2) + tid; e < cnt; e += BT)
            acc_edge(S, bin[e], ph[bin[e] >> SHIFT]);
    }
    __syncthreads();
    // coalesced flush of the whole tile (zeros included -> no init needed)
    float4* dst = Spart + (size_t)blockIdx.x * NP;
    for (int k = tid; k < NP; k += BT) {
        float4 o;
        o.x = S[k * 5 + 0]; o.y = S[k * 5 + 1];
        o.z = S[k * 5 + 2]; o.w = S[k * 5 + 3];
        dst[k] = o;
    }
}

// combine partials + self-loop, tanh, grid-reduce -> gsum
__global__ __launch_bounds__(BT) void k_tanh(const float4* __restrict__ Spart,
                                             const Half4* __restrict__ ph,
                                             const float* __restrict__ dinvg,
                                             const float* __restrict__ conv_b,
                                             int n, int SUB, float* __restrict__ gsum) {
    int node = blockIdx.x * BT + threadIdx.x;
    float4 acc = {0.f, 0.f, 0.f, 0.f};
    if (node < n) {
        int part = node >> SHIFT;
        int local = node & MASK;
        float4 s = {0.f, 0.f, 0.f, 0.f};
        for (int sub = 0; sub < SUB; ++sub) {
            float4 t = Spart[((size_t)(part * SUB + sub)) * NP + local];
            s.x += t.x; s.y += t.y; s.z += t.z; s.w += t.w;
        }
        float di = dinvg[node];
        Half4 hp = ph[node];
        float2 pa = __half22float2(hp.a), pb = __half22float2(hp.b);
        acc.x = tanhf(di * (s.x + pa.x) + conv_b[0]);
        acc.y = tanhf(di * (s.y + pa.y) + conv_b[1]);
        acc.z = tanhf(di * (s.z + pb.x) + conv_b[2]);
        acc.w = tanhf(di * (s.w + pb.y) + conv_b[3]);
    }
#pragma unroll
    for (int off = 32; off > 0; off >>= 1) {
        acc.x += __shfl_down(acc.x, off);
        acc.y += __shfl_down(acc.y, off);
        acc.z += __shfl_down(acc.z, off);
        acc.w += __shfl_down(acc.w, off);
    }
    __shared__ float4 red[BT / 64];
    int lane = threadIdx.x & 63, wv = threadIdx.x >> 6;
    if (lane == 0) red[wv] = acc;
    __syncthreads();
    if (threadIdx.x == 0) {
        float4 tt = red[0];
        for (int k = 1; k < BT / 64; ++k) {
            tt.x += red[k].x; tt.y += red[k].y; tt.z += red[k].z; tt.w += red[k].w;
        }
        unsafeAtomicAdd(&gsum[0], tt.x);
        unsafeAtomicAdd(&gsum[1], tt.y);
        unsafeAtomicAdd(&gsum[2], tt.z);
        unsafeAtomicAdd(&gsum[3], tt.w);
    }
}

__global__ void k_head(const float* __restrict__ gsum,
                       const float* __restrict__ fc1w, const float* __restrict__ fc1b,
                       const float* __restrict__ fc3w, const float* __restrict__ fc3b,
                       float* __restrict__ out, int n) {
    __shared__ float hdn[64];
    int t = threadIdx.x;
    float g[4];
    float inv_n = 1.0f / (float)n;
#pragma unroll
    for (int j = 0; j < 4; ++j) g[j] = gsum[j] * inv_n;
    if (t < 64) {
        float a = fc1b[t];
#pragma unroll
        for (int j = 0; j < 4; ++j) a += g[j] * fc1w[t * 4 + j];
        hdn[t] = fmaxf(a, 0.f);
    }
    __syncthreads();
    if (t < 10) {
        float a = fc3b[t];
#pragma unroll
        for (int k = 0; k < 64; ++k) a += hdn[k] * fc3w[t * 64 + k];
        out[t] = a;
    }
}

// ---------------- fallback path (round-1, global atomics) ----------------

__global__ void k_deg(const int* __restrict__ col, int n_edges, int* __restrict__ deg) {
    int t = blockIdx.x * blockDim.x + threadIdx.x;
    int base = t * 4;
    if (base + 4 <= n_edges) {
        int4 c = *(const int4*)(col + base);
        atomicAdd(&deg[c.x], 1); atomicAdd(&deg[c.y], 1);
        atomicAdd(&deg[c.z], 1); atomicAdd(&deg[c.w], 1);
    } else {
        for (int e = base; e < n_edges; ++e) atomicAdd(&deg[col[e]], 1);
    }
}

__global__ void k_node(const float* __restrict__ x, const float* __restrict__ conv_w,
                       const int* __restrict__ deg, float4* __restrict__ p, int n) {
    int i = blockIdx.x * blockDim.x + threadIdx.x;
    if (i >= n) return;
    const float* xr = x + (size_t)i * 6;
    float2 a = *(const float2*)xr;
    float2 b = *(const float2*)(xr + 2);
    float2 c = *(const float2*)(xr + 4);
    float xv[6] = {a.x, a.y, b.x, b.y, c.x, c.y};
    float dinv = rsqrtf((float)(deg[i] + 1));
    float h0 = 0.f, h1 = 0.f, h2 = 0.f, h3 = 0.f;
#pragma unroll
    for (int j = 0; j < 6; ++j) {
        h0 += xv[j] * conv_w[j];
        h1 += xv[j] * conv_w[6 + j];
        h2 += xv[j] * conv_w[12 + j];
        h3 += xv[j] * conv_w[18 + j];
    }
    float4 o; o.x = h0 * dinv; o.y = h1 * dinv; o.z = h2 * dinv; o.w = h3 * dinv;
    p[i] = o;
}

__global__ void k_scatter(const int* __restrict__ row, const int* __restrict__ col, int n_edges,
                          const float4* __restrict__ p, float* __restrict__ S) {
    int t = blockIdx.x * blockDim.x + threadIdx.x;
    int base = t * 2;
    if (base + 2 <= n_edges) {
        int2 r = *(const int2*)(row + base);
        int2 c = *(const int2*)(col + base);
        float4 p0 = p[r.x], p1 = p[r.y];
        float* s0 = S + 4 * c.x;
        unsafeAtomicAdd(s0 + 0, p0.x); unsafeAtomicAdd(s0 + 1, p0.y);
        unsafeAtomicAdd(s0 + 2, p0.z); unsafeAtomicAdd(s0 + 3, p0.w);
        float* s1 = S + 4 * c.y;
        unsafeAtomicAdd(s1 + 0, p1.x); unsafeAtomicAdd(s1 + 1, p1.y);
        unsafeAtomicAdd(s1 + 2, p1.z); unsafeAtomicAdd(s1 + 3, p1.w);
    } else {
        for (int e = base; e < n_edges; ++e) {
            int r = row[e], c = col[e];
            float4 pv = p[r];
            float* s = S + 4 * c;
            unsafeAtomicAdd(s + 0, pv.x); unsafeAtomicAdd(s + 1, pv.y);
            unsafeAtomicAdd(s + 2, pv.z); unsafeAtomicAdd(s + 3, pv.w);
        }
    }
}

__global__ void k_reduce(const float4* __restrict__ S4, const float4* __restrict__ p,
                         const int* __restrict__ deg, const float* __restrict__ conv_b,
                         int n, float* __restrict__ gsum) {
    int i = blockIdx.x * blockDim.x + threadIdx.x;
    float4 v = {0.f, 0.f, 0.f, 0.f};
    if (i < n) {
        float dinv = rsqrtf((float)(deg[i] + 1));
        float4 s = S4[i];
        float4 pp = p[i];
        v.x = tanhf(dinv * (s.x + pp.x) + conv_b[0]);
        v.y = tanhf(dinv * (s.y + pp.y) + conv_b[1]);
        v.z = tanhf(dinv * (s.z + pp.z) + conv_b[2]);
        v.w = tanhf(dinv * (s.w + pp.w) + conv_b[3]);
    }
#pragma unroll
    for (int off = 32; off > 0; off >>= 1) {
        v.x += __shfl_down(v.x, off);
        v.y += __shfl_down(v.y, off);
        v.z += __shfl_down(v.z, off);
        v.w += __shfl_down(v.w, off);
    }
    __shared__ float4 lds[4];
    int lane = threadIdx.x & 63, w = threadIdx.x >> 6;
    if (lane == 0) lds[w] = v;
    __syncthreads();
    if (threadIdx.x == 0) {
        float4 tt = lds[0];
        for (int k = 1; k < 4; ++k) {
            tt.x += lds[k].x; tt.y += lds[k].y; tt.z += lds[k].z; tt.w += lds[k].w;
        }
        unsafeAtomicAdd(&gsum[0], tt.x); unsafeAtomicAdd(&gsum[1], tt.y);
        unsafeAtomicAdd(&gsum[2], tt.z); unsafeAtomicAdd(&gsum[3], tt.w);
    }
}

// ---------------- launch ----------------

extern "C" void kernel_launch(void* const* d_in, const int* in_sizes, int n_in,
                              void* d_out, int out_size, void* d_ws, size_t ws_size,
                              hipStream_t stream) {
    const float* x      = (const float*)d_in[0];
    const int*   ei     = (const int*)d_in[1];
    const float* conv_w = (const float*)d_in[2];
    const float* conv_b = (const float*)d_in[3];
    const float* fc1w   = (const float*)d_in[4];
    const float* fc1b   = (const float*)d_in[5];
    const float* fc3w   = (const float*)d_in[6];
    const float* fc3b   = (const float*)d_in[7];

    int n = in_sizes[0] / 6;
    int E = in_sizes[1] / 2;
    const int* row = ei;       // edge_index[0] = source
    const int* col = ei + E;   // edge_index[1] = target

    int P = (n + NP - 1) / NP;
    int avg = (E + P - 1) / P;
    int cap = ((avg + avg / 32 + 256) + 15) & ~15;   // ~7 sigma headroom

    // ws layout: cursor[P] | gsum[4] | dinv[n] | ph[n] | binned[P*cap] | Spart[P*SUB*NP*4]
    size_t off = 0;
    size_t cursor_off = off;          off += (size_t)P * sizeof(int);
    off = (off + 15) & ~(size_t)15;
    size_t gsum_off = off;            off += 4 * sizeof(float);
    size_t zero_end = off;
    off = (off + 15) & ~(size_t)15;
    size_t dinv_off = off;            off += (size_t)n * sizeof(float);
    off = (off + 15) & ~(size_t)15;
    size_t ph_off = off;              off += (size_t)n * sizeof(Half4);
    off = (off + 15) & ~(size_t)15;
    size_t bin_off = off;             off += (size_t)P * cap * sizeof(unsigned);
    off = (off + 255) & ~(size_t)255;
    size_t spart_off = off;
    size_t spart_bytes1 = (size_t)P * NP * sizeof(float4);   // per SUB level

    char* ws = (char*)d_ws;
    int SUB = 0;
    if (ws_size >= spart_off + 2 * spart_bytes1 && P <= NPART_MAX && n < (1 << 22)) SUB = 2;
    else if (ws_size >= spart_off + spart_bytes1 && P <= NPART_MAX && n < (1 << 22)) SUB = 1;

    if (SUB > 0) {
        int* cursor = (int*)(ws + cursor_off);
        float* gsum = (float*)(ws + gsum_off);
        float* dinvg = (float*)(ws + dinv_off);
        Half4* ph = (Half4*)(ws + ph_off);
        unsigned* binned = (unsigned*)(ws + bin_off);
        float4* Spart = (float4*)(ws + spart_off);

        hipMemsetAsync(d_ws, 0, zero_end, stream);
        int bin_blocks = (E + EPB - 1) / EPB;
        k_bin<<<bin_blocks, BINB, 0, stream>>>(row, col, E, P, cap, cursor, binned);
        k_part_node<<<P, BT, 0, stream>>>(binned, cursor, cap, x, conv_w, n, ph, dinvg);
        k_acc2<<<P * SUB, BT, 0, stream>>>(binned, cursor, cap, ph, SUB, Spart);
        k_tanh<<<(n + BT - 1) / BT, BT, 0, stream>>>(Spart, ph, dinvg, conv_b, n, SUB, gsum);
        k_head<<<1, 64, 0, stream>>>(gsum, fc1w, fc1b, fc3w, fc3b, (float*)d_out, n);
    } else {
        size_t o = 0;
        int* deg = (int*)(ws + o);      o += (size_t)n * sizeof(int);
        o = (o + 15) & ~(size_t)15;
        float* S = (float*)(ws + o);    o += (size_t)n * 4 * sizeof(float);
        float* gsum = (float*)(ws + o);
        size_t zend = o + 4 * sizeof(float);
        o = (zend + 15) & ~(size_t)15;
        float4* p = (float4*)(ws + o);

        hipMemsetAsync(d_ws, 0, zend, stream);
        int t1 = (E + 3) / 4;
        k_deg<<<(t1 + 255) / 256, 256, 0, stream>>>(col, E, deg);
        k_node<<<(n + 255) / 256, 256, 0, stream>>>(x, conv_w, deg, p, n);
        int t3 = (E + 1) / 2;
        k_scatter<<<(t3 + 255) / 256, 256, 0, stream>>>(row, col, E, p, S);
        k_reduce<<<(n + 255) / 256, 256, 0, stream>>>((const float4*)S, p, deg, conv_b, n, gsum);
        k_head<<<1, 64, 0, stream>>>(gsum, fc1w, fc1b, fc3w, fc3b, (float*)d_out, n);
    }
}